// Round 3
// baseline (1044.066 us; speedup 1.0000x reference)
//
#include <hip/hip_runtime.h>
#include <math.h>

// Problem constants
#define RR 16384        // B*N rows
#define DD 512          // feature dim
#define CC 4096         // codebook size
#define QQ 4            // num quantizers
#define NB 16           // codebook n-chunks (CC/256) -- R2: 256-col sim blocks
#define QOUT_SZ (RR*DD)
#define IDX_OFF QOUT_SZ
#define LOSS_OFF (QOUT_SZ + RR*QQ)
#define LOSS_COEF (1.25f / 8388608.0f)
#define NBLK_FIN (RR/4)  // finalize blocks per dispatch (4096)

// Workspace layout (float offsets) -- offsets kept from R1 for stability
#define WS_RESID 0
#define WS_CBN   (RR*DD)                    // 8388608
#define WS_RNRM  (WS_CBN + CC*DD)           // 10485760
#define WS_PV    (WS_RNRM + RR)             // 10502144  (pk: RR*NB*4 u32, fits old region)
#define WS_PI    (WS_PV + RR*32*4)          // loss partials [QQ][NBLK_FIN]
#define WS_F16   (WS_PI + RR*32*4 + 4)      // 16B aligned
// f16 region (offsets in halves from WS_F16 base)
#define F16_A 0
#define F16_B (RR*DD)

typedef _Float16 f16x8 __attribute__((ext_vector_type(8)));
typedef float f32x4 __attribute__((ext_vector_type(4)));

__device__ __forceinline__ float waveSum(float v) {
#pragma unroll
    for (int m = 1; m < 64; m <<= 1) v += __shfl_xor(v, m, 64);
    return v;
}

// interleaved N-way wave sum: N independent butterfly chains for ILP
template <int N>
__device__ __forceinline__ void waveSumN(float* v) {
#pragma unroll
    for (int m = 1; m < 64; m <<= 1) {
#pragma unroll
        for (int j = 0; j < N; ++j) v[j] += __shfl_xor(v[j], m, 64);
    }
}

// ---------- packed-key top-4 machinery ----------
// key = monotone(f32 sim) truncated to top-20 bits | (4095 - col).
__device__ __forceinline__ unsigned packKey(float v, int c) {
    unsigned u = __float_as_uint(v);
    u ^= (unsigned)((int)u >> 31) | 0x80000000u;   // monotone total order
    return (u & 0xFFFFF000u) | (unsigned)(4095 - c);
}

__device__ __forceinline__ void ceDesc(unsigned &a, unsigned &b) {
    unsigned mn = a > b ? b : a;
    a = a > b ? a : b;
    b = mn;
}

__device__ __forceinline__ void sort4(unsigned k[4]) {
    ceDesc(k[0], k[1]); ceDesc(k[2], k[3]);
    ceDesc(k[0], k[2]); ceDesc(k[1], k[3]);
    ceDesc(k[1], k[2]);
}

__device__ __forceinline__ void merge4(unsigned k[4],
                                       unsigned b0, unsigned b1,
                                       unsigned b2, unsigned b3) {
    k[0] = k[0] > b3 ? k[0] : b3;
    k[1] = k[1] > b2 ? k[1] : b2;
    k[2] = k[2] > b1 ? k[2] : b1;
    k[3] = k[3] > b0 ? k[3] : b0;
    ceDesc(k[0], k[2]); ceDesc(k[1], k[3]);
    ceDesc(k[0], k[1]); ceDesc(k[2], k[3]);
}

__device__ __forceinline__ void merge4Shfl(unsigned k[4], int m) {
    unsigned b0 = __shfl_xor(k[0], m, 64);
    unsigned b1 = __shfl_xor(k[1], m, 64);
    unsigned b2 = __shfl_xor(k[2], m, 64);
    unsigned b3 = __shfl_xor(k[3], m, 64);
    merge4(k, b0, b1, b2, b3);
}

// ---------------- init: resid = x, qout = 0 ----------------
__global__ void initK(const float* __restrict__ x, float* __restrict__ resid,
                      float* __restrict__ dout) {
    int i = blockIdx.x * blockDim.x + threadIdx.x;
    int stride = gridDim.x * blockDim.x;
    for (; i < QOUT_SZ; i += stride) { resid[i] = x[i]; dout[i] = 0.0f; }
}

// ---------------- implicit_cb = codebooks[q] @ weights[q]^T ----------------
__global__ __launch_bounds__(256) void gemmCbK(const float* __restrict__ A,
                                               const float* __restrict__ W,
                                               float* __restrict__ out) {
    __shared__ float As[32][64];
    __shared__ float Bs[32][64];
    int t = threadIdx.x;
    int tx = t & 15, ty = t >> 4;
    int cBase = blockIdx.x * 64;
    int dBase = blockIdx.y * 64;
    int f = t & 7;
    int mq = t >> 3;
    float acc[4][4] = {};
    for (int k0 = 0; k0 < DD; k0 += 32) {
        __syncthreads();
#pragma unroll
        for (int p = 0; p < 2; ++p) {
            int m = mq + p * 32;
            float4 av = *(const float4*)&A[(size_t)(cBase + m) * DD + k0 + f * 4];
            As[f*4+0][m] = av.x; As[f*4+1][m] = av.y; As[f*4+2][m] = av.z; As[f*4+3][m] = av.w;
            float4 wv = *(const float4*)&W[(size_t)(dBase + m) * DD + k0 + f * 4];
            Bs[f*4+0][m] = wv.x; Bs[f*4+1][m] = wv.y; Bs[f*4+2][m] = wv.z; Bs[f*4+3][m] = wv.w;
        }
        __syncthreads();
#pragma unroll
        for (int kk = 0; kk < 32; ++kk) {
            float4 a4 = *(const float4*)&As[kk][ty * 4];
            float4 b4 = *(const float4*)&Bs[kk][tx * 4];
            float a[4] = {a4.x, a4.y, a4.z, a4.w};
            float b[4] = {b4.x, b4.y, b4.z, b4.w};
#pragma unroll
            for (int i = 0; i < 4; ++i)
#pragma unroll
                for (int j = 0; j < 4; ++j) acc[i][j] += a[i] * b[j];
        }
    }
#pragma unroll
    for (int i = 0; i < 4; ++i) {
        float4 v = make_float4(acc[i][0], acc[i][1], acc[i][2], acc[i][3]);
        *(float4*)&out[(size_t)(cBase + ty * 4 + i) * DD + dBase + tx * 4] = v;
    }
}

// ------- normalize cbn rows in place + emit f16 copy (one wave/row) ----------
__global__ void rowNormCvtK(float* __restrict__ buf, _Float16* __restrict__ bf16) {
    int wave = threadIdx.x >> 6, lane = threadIdx.x & 63;
    int row = blockIdx.x * 4 + wave;
    float* p = buf + (size_t)row * DD;
    float4 v0 = *(float4*)&p[lane * 8];
    float4 v1 = *(float4*)&p[lane * 8 + 4];
    float ss = v0.x*v0.x + v0.y*v0.y + v0.z*v0.z + v0.w*v0.w
             + v1.x*v1.x + v1.y*v1.y + v1.z*v1.z + v1.w*v1.w;
    ss = waveSum(ss);
    float nrm = fmaxf(sqrtf(ss), 1e-12f);
    float vals[8] = {v0.x/nrm, v0.y/nrm, v0.z/nrm, v0.w/nrm,
                     v1.x/nrm, v1.y/nrm, v1.z/nrm, v1.w/nrm};
    *(float4*)&p[lane * 8]     = make_float4(vals[0], vals[1], vals[2], vals[3]);
    *(float4*)&p[lane * 8 + 4] = make_float4(vals[4], vals[5], vals[6], vals[7]);
    f16x8 hv;
#pragma unroll
    for (int j = 0; j < 8; ++j) hv[j] = (_Float16)vals[j];
    *(f16x8*)&bf16[(size_t)row * DD + lane * 8] = hv;
}

// ------- resid row norms + f16 copy of RAW resid (q=0 only) ------------------
__global__ void residCvtK(const float* __restrict__ resid,
                          float* __restrict__ rnrm, _Float16* __restrict__ af16) {
    int wave = threadIdx.x >> 6, lane = threadIdx.x & 63;
    int row = blockIdx.x * 4 + wave;
    const float* p = resid + (size_t)row * DD;
    float4 v0 = *(const float4*)&p[lane * 8];
    float4 v1 = *(const float4*)&p[lane * 8 + 4];
    float vals[8] = {v0.x, v0.y, v0.z, v0.w, v1.x, v1.y, v1.z, v1.w};
    float ss = 0.f;
#pragma unroll
    for (int j = 0; j < 8; ++j) ss += vals[j] * vals[j];
    ss = waveSum(ss);
    if (lane == 0) rnrm[row] = fmaxf(sqrtf(ss), 1e-12f);
    f16x8 hv;
#pragma unroll
    for (int j = 0; j < 8; ++j) hv[j] = (_Float16)vals[j];
    *(f16x8*)&af16[(size_t)row * DD + lane * 8] = hv;
}

// ---------------- single-pass f16 MFMA sim GEMM + fused top-4 ----------------
// R2: 128x256 block, 8 waves (2M x 4N), 64x64 wave tile (acc[4][4]), BK=64,
// DOUBLE-BUFFERED LDS with 2-phase schedule: stage(t+1) issued before
// compute(t), ONE __syncthreads per K-step (implicit vmcnt(0) drains the
// prefetch after compute covered its latency). R1 counters showed 21.7%
// MfmaUtil / 34% VALU / 6% HBM = LDS-read + barrier-drain bound: old tile had
// 768 B LDS-read per MFMA (>40% util impossible) and two full-drain barriers
// per K-step with staging serialized between them. New: 512 B/MFMA, 2x MFMA
// per barrier, loads overlapped. LDS 96 KB -> 1 block/CU (precedent: 8-phase
// template at 128 KB). sK reuses dead Alds after the main loop.
__global__ __launch_bounds__(512, 2)
void simMfmaK(
    const _Float16* __restrict__ Af16, const _Float16* __restrict__ Bf16,
    unsigned* __restrict__ pk) {
    __shared__ _Float16 Alds[2][128 * 64];   // 32 KB
    __shared__ _Float16 Blds[2][256 * 64];   // 64 KB
    int t = threadIdx.x, w = t >> 6, lane = t & 63;
    int rowBase = blockIdx.x * 128;
    int cBase = blockIdx.y * 256;
    int mbase = (w & 1) * 64, nbase = (w >> 1) * 64;
    int l15 = lane & 15, quad = lane >> 4;

    f32x4 acc[4][4];
#pragma unroll
    for (int i = 0; i < 4; ++i)
#pragma unroll
        for (int j = 0; j < 4; ++j) acc[i][j] = (f32x4){0.f, 0.f, 0.f, 0.f};

    // staging: lane covers 16 B; 8 lanes per 128-B row; wave w stages rows
    // 8w..8w+7 of each 64-row group. Source chunk XOR-swizzled so LDS row r
    // holds chunk c at slot c^(r&7); dest stays contiguous (wave-uniform base).
    int rsub = lane >> 3;                 // 0..7 row within the wave's 8-row group
    int swz = (lane & 7) ^ rsub;          // source 16B-chunk index

    // prologue: stage tile 0 into buffer 0
#pragma unroll
    for (int j = 0; j < 2; ++j) {
        int rA = rowBase + j * 64 + 8 * w + rsub;
        __builtin_amdgcn_global_load_lds(
            (const __attribute__((address_space(1))) void*)&Af16[(size_t)rA * DD + swz * 8],
            (__attribute__((address_space(3))) void*)&Alds[0][(j * 64 + 8 * w) * 64], 16, 0, 0);
    }
#pragma unroll
    for (int j = 0; j < 4; ++j) {
        int rB = cBase + j * 64 + 8 * w + rsub;
        __builtin_amdgcn_global_load_lds(
            (const __attribute__((address_space(1))) void*)&Bf16[(size_t)rB * DD + swz * 8],
            (__attribute__((address_space(3))) void*)&Blds[0][(j * 64 + 8 * w) * 64], 16, 0, 0);
    }
    __syncthreads();   // implicit vmcnt(0): tile 0 landed

#pragma unroll
    for (int tt = 0; tt < 8; ++tt) {
        int buf = tt & 1;
        // phase 1: issue next tile's loads into the other buffer
        if (tt < 7) {
            int k0 = (tt + 1) * 64;
#pragma unroll
            for (int j = 0; j < 2; ++j) {
                int rA = rowBase + j * 64 + 8 * w + rsub;
                __builtin_amdgcn_global_load_lds(
                    (const __attribute__((address_space(1))) void*)&Af16[(size_t)rA * DD + k0 + swz * 8],
                    (__attribute__((address_space(3))) void*)&Alds[buf ^ 1][(j * 64 + 8 * w) * 64], 16, 0, 0);
            }
#pragma unroll
            for (int j = 0; j < 4; ++j) {
                int rB = cBase + j * 64 + 8 * w + rsub;
                __builtin_amdgcn_global_load_lds(
                    (const __attribute__((address_space(1))) void*)&Bf16[(size_t)rB * DD + k0 + swz * 8],
                    (__attribute__((address_space(3))) void*)&Blds[buf ^ 1][(j * 64 + 8 * w) * 64], 16, 0, 0);
            }
        }
        // phase 2: compute current buffer
#pragma unroll
        for (int kh = 0; kh < 2; ++kh) {
            int chunk = (kh * 4 + quad) ^ (l15 & 7);   // row&7 == l15&7 for all tiles
            f16x8 af[4], bf[4];
#pragma unroll
            for (int tm = 0; tm < 4; ++tm)
                af[tm] = *(const f16x8*)&Alds[buf][(mbase + tm * 16 + l15) * 64 + chunk * 8];
#pragma unroll
            for (int tn = 0; tn < 4; ++tn)
                bf[tn] = *(const f16x8*)&Blds[buf][(nbase + tn * 16 + l15) * 64 + chunk * 8];
#pragma unroll
            for (int tn = 0; tn < 4; ++tn)
#pragma unroll
                for (int tm = 0; tm < 4; ++tm)
                    acc[tm][tn] = __builtin_amdgcn_mfma_f32_16x16x32_f16(
                        af[tm], bf[tn], acc[tm][tn], 0, 0, 0);
        }
        __syncthreads();   // implicit vmcnt(0)+lgkmcnt(0): prefetch landed,
                           // all waves done reading buf -> safe to overwrite
    }

    // epilogue: per wave, top-4 per row over its 64 columns, packed keys.
    // D layout: lane,reg r -> row = quad*4+r (in 16-tile), col = l15
    // sK aliases dead Alds: [4 ngroups][128 rows][4 keys] = 8 KB (< 32 KB)
    unsigned* sKp = (unsigned*)&Alds[0][0];
#pragma unroll
    for (int tm = 0; tm < 4; ++tm) {
#pragma unroll
        for (int r = 0; r < 4; ++r) {
            unsigned k[4];
#pragma unroll
            for (int tn = 0; tn < 4; ++tn)
                k[tn] = packKey(acc[tm][tn][r], cBase + nbase + tn * 16 + l15);
            sort4(k);
#pragma unroll
            for (int m = 1; m < 16; m <<= 1) merge4Shfl(k, m);
            if (l15 == 0) {
                int rowl = mbase + tm * 16 + quad * 4 + r;
                int ng = w >> 1;                // which 64-col quarter
#pragma unroll
                for (int j = 0; j < 4; ++j) sKp[(ng * 128 + rowl) * 4 + j] = k[j];
            }
        }
    }
    __syncthreads();
    if (t < 128) {
        unsigned k[4];
#pragma unroll
        for (int j = 0; j < 4; ++j) k[j] = sKp[t * 4 + j];
#pragma unroll
        for (int g = 1; g < 4; ++g)
            merge4(k, sKp[(g * 128 + t) * 4 + 0], sKp[(g * 128 + t) * 4 + 1],
                      sKp[(g * 128 + t) * 4 + 2], sKp[(g * 128 + t) * 4 + 3]);
        size_t o = ((size_t)(rowBase + t) * NB + blockIdx.y) * 4;
#pragma unroll
        for (int j = 0; j < 4; ++j) pk[o + j] = k[j];
    }
}

// -------- finalize: merge chunk top-4s, fp32 rescore, rotation, updates,
//          and emit next-q residual f16 + rnrm (fused residCvt) --------------
__global__ void finalizeK(float* __restrict__ resid,
                          float* __restrict__ rnrm,
                          const float* __restrict__ cbn,
                          const unsigned* __restrict__ pk,
                          float* __restrict__ dout,
                          float* __restrict__ lossPart,
                          _Float16* __restrict__ af16, int q) {
    __shared__ float sL[4];
    int wave = threadIdx.x >> 6, lane = threadIdx.x & 63;
    int row = blockIdx.x * 4 + wave;
    float* xr = resid + (size_t)row * DD;
    float nrm = rnrm[row];
    float4 a0 = *(float4*)&xr[lane * 8];
    float4 a1 = *(float4*)&xr[lane * 8 + 4];
    float orig[8] = {a0.x,a0.y,a0.z,a0.w,a1.x,a1.y,a1.z,a1.w};
    float x[8];
#pragma unroll
    for (int j = 0; j < 8; ++j) x[j] = orig[j] / nrm;   // x_n per reference

    // merge NB=16 chunk top-4 partials (lane i < 16 loads chunk i)
    unsigned k[4] = {0u, 0u, 0u, 0u};
    if (lane < NB) {
        size_t o = ((size_t)row * NB + lane) * 4;
#pragma unroll
        for (int j = 0; j < 4; ++j) k[j] = pk[o + j];
    }
#pragma unroll
    for (int m = 1; m < 16; m <<= 1) merge4Shfl(k, m);
    int cand[4];
#pragma unroll
    for (int j = 0; j < 4; ++j)
        cand[j] = 4095 - (int)(__shfl(k[j], 0, 64) & 0xFFFu);

    // exact fp32 rescore of the 4 nominated candidates on the normalized row.
    float cv[4][8];
#pragma unroll
    for (int j = 0; j < 4; ++j) {
        const float* cbj = cbn + (size_t)cand[j] * DD;
        float4 c0 = *(const float4*)&cbj[lane * 8];
        float4 c1 = *(const float4*)&cbj[lane * 8 + 4];
        cv[j][0]=c0.x; cv[j][1]=c0.y; cv[j][2]=c0.z; cv[j][3]=c0.w;
        cv[j][4]=c1.x; cv[j][5]=c1.y; cv[j][6]=c1.z; cv[j][7]=c1.w;
    }
    float s[4];
#pragma unroll
    for (int j = 0; j < 4; ++j) {
        float acc = 0.f;
#pragma unroll
        for (int e = 0; e < 8; ++e) acc += x[e] * cv[j][e];
        s[j] = acc;
    }
    waveSumN<4>(s);
    float sBest = -3e38f; int idx = 0x7fffffff, sel = 0;
#pragma unroll
    for (int j = 0; j < 4; ++j) {
        if (s[j] > sBest || (s[j] == sBest && cand[j] < idx)) {
            sBest = s[j]; idx = cand[j]; sel = j;
        }
    }

    // winning row from registers (wave-uniform sel -> cndmask tree)
    float qv[8];
#pragma unroll
    for (int e = 0; e < 8; ++e)
        qv[e] = sel == 0 ? cv[0][e] : sel == 1 ? cv[1][e]
              : sel == 2 ? cv[2][e] : cv[3][e];

    float red3[3] = {0.f, 0.f, 0.f};   // ns2, nt2, lrow
#pragma unroll
    for (int j = 0; j < 8; ++j) {
        red3[0] += x[j] * x[j];
        red3[1] += qv[j] * qv[j];
        float d = x[j] - qv[j];
        red3[2] += d * d;
    }
    waveSumN<3>(red3);
    float ns = sqrtf(red3[0]), nt = sqrtf(red3[1]), lrow = red3[2];

    float u[8], qn[8], wv[8];
    float nw2 = 0.f;
#pragma unroll
    for (int j = 0; j < 8; ++j) {
        u[j] = x[j] / ns;
        qn[j] = qv[j] / nt;
        wv[j] = u[j] + qn[j];
        nw2 += wv[j] * wv[j];
    }
    nw2 = waveSum(nw2);
    float nw = fmaxf(sqrtf(nw2), 1e-12f);
    float red2[2] = {0.f, 0.f};        // dew, deu
#pragma unroll
    for (int j = 0; j < 8; ++j) {
        wv[j] = wv[j] / nw;
        red2[0] += x[j] * wv[j];
        red2[1] += x[j] * u[j];
    }
    waveSumN<2>(red2);
    float dew = red2[0], deu = red2[1];
    float scale = nt / ns;

    float r[8], nres[8];
    float ss = 0.f;
#pragma unroll
    for (int j = 0; j < 8; ++j) {
        r[j] = (x[j] - 2.0f * dew * wv[j] + 2.0f * deu * qn[j]) * scale;
        nres[j] = orig[j] - r[j];
        ss += nres[j] * nres[j];
    }

    // residual -= r ; emit f16 residual + next rnrm (fused residCvt)
    *(float4*)&xr[lane * 8]     = make_float4(nres[0], nres[1], nres[2], nres[3]);
    *(float4*)&xr[lane * 8 + 4] = make_float4(nres[4], nres[5], nres[6], nres[7]);
    ss = waveSum(ss);
    if (lane == 0) rnrm[row] = fmaxf(sqrtf(ss), 1e-12f);
    f16x8 hv;
#pragma unroll
    for (int j = 0; j < 8; ++j) hv[j] = (_Float16)nres[j];
    *(f16x8*)&af16[(size_t)row * DD + lane * 8] = hv;

    float* op = dout + (size_t)row * DD;
    float4 o0 = *(float4*)&op[lane * 8];
    float4 o1 = *(float4*)&op[lane * 8 + 4];
    o0.x += r[0]; o0.y += r[1]; o0.z += r[2]; o0.w += r[3];
    o1.x += r[4]; o1.y += r[5]; o1.z += r[6]; o1.w += r[7];
    *(float4*)&op[lane * 8] = o0;
    *(float4*)&op[lane * 8 + 4] = o1;

    if (lane == 0) {
        dout[IDX_OFF + row * 4 + q] = (float)idx;
        sL[wave] = lrow;
    }
    __syncthreads();
    if (threadIdx.x == 0) {
        lossPart[(size_t)q * NBLK_FIN + blockIdx.x] =
            (sL[0] + sL[1] + sL[2] + sL[3]) * LOSS_COEF;
    }
}

// -------- final loss reduce: one wave per q sums its 4096 block partials -----
__global__ void lossWriteK(const float* __restrict__ lossPart,
                           float* __restrict__ dout) {
    int q = threadIdx.x >> 6, lane = threadIdx.x & 63;
    float s = 0.f;
    for (int i = lane; i < NBLK_FIN; i += 64)
        s += lossPart[(size_t)q * NBLK_FIN + i];
    s = waveSum(s);
    if (lane == 0) dout[LOSS_OFF + q] = s;
}

extern "C" void kernel_launch(void* const* d_in, const int* in_sizes, int n_in,
                              void* d_out, int out_size, void* d_ws, size_t ws_size,
                              hipStream_t stream) {
    const float* x = (const float*)d_in[0];
    const float* codebooks = (const float*)d_in[1];
    const float* weights = (const float*)d_in[2];
    float* dout = (float*)d_out;
    float* w = (float*)d_ws;

    float* resid = w + WS_RESID;
    float* cbn   = w + WS_CBN;
    float* rnrm  = w + WS_RNRM;
    unsigned* pk = (unsigned*)(w + WS_PV);
    float* lossPart = w + WS_PI;
    _Float16* f16base = (_Float16*)(w + WS_F16);
    _Float16* Af16 = f16base + F16_A;
    _Float16* Bf16 = f16base + F16_B;

    initK<<<4096, 256, 0, stream>>>(x, resid, dout);
    residCvtK<<<RR / 4, 256, 0, stream>>>(resid, rnrm, Af16);

    for (int q = 0; q < QQ; ++q) {
        gemmCbK<<<dim3(CC / 64, DD / 64), 256, 0, stream>>>(
            codebooks + (size_t)q * CC * DD, weights + (size_t)q * DD * DD, cbn);
        rowNormCvtK<<<CC / 4, 256, 0, stream>>>(cbn, Bf16);
        simMfmaK<<<dim3(RR / 128, CC / 256), 512, 0, stream>>>(Af16, Bf16, pk);
        finalizeK<<<RR / 4, 256, 0, stream>>>(resid, rnrm, cbn, pk,
                                              dout, lossPart, Af16, q);
    }
    lossWriteK<<<1, 256, 0, stream>>>(lossPart, dout);
}

// Round 4
// 1034.569 us; speedup vs baseline: 1.0092x; 1.0092x over previous
//
#include <hip/hip_runtime.h>
#include <math.h>

// Problem constants
#define RR 16384        // B*N rows
#define DD 512          // feature dim
#define CC 4096         // codebook size
#define QQ 4            // num quantizers
#define NB 32           // codebook n-chunks (CC/128)
#define QOUT_SZ (RR*DD)
#define IDX_OFF QOUT_SZ
#define LOSS_OFF (QOUT_SZ + RR*QQ)
#define LOSS_COEF (1.25f / 8388608.0f)
#define NBLK_FIN (RR/4)  // finalize blocks per dispatch (4096)

// Workspace layout (float offsets)
#define WS_RESID 0
#define WS_CBN   (RR*DD)                    // 8388608
#define WS_RNRM  (WS_CBN + CC*DD)           // 10485760
#define WS_PV    (WS_RNRM + RR)             // 10502144  (pk: RR*NB*4 u32 keys)
#define WS_PI    (WS_PV + RR*32*4)          // loss partials [QQ][NBLK_FIN]
#define WS_F16   (WS_PI + RR*32*4 + 4)      // 16B aligned
// f16 region (offsets in halves from WS_F16 base)
#define F16_A 0
#define F16_B (RR*DD)

typedef _Float16 f16x8 __attribute__((ext_vector_type(8)));
typedef float f32x4 __attribute__((ext_vector_type(4)));

__device__ __forceinline__ float waveSum(float v) {
#pragma unroll
    for (int m = 1; m < 64; m <<= 1) v += __shfl_xor(v, m, 64);
    return v;
}

// interleaved N-way wave sum: N independent butterfly chains for ILP
template <int N>
__device__ __forceinline__ void waveSumN(float* v) {
#pragma unroll
    for (int m = 1; m < 64; m <<= 1) {
#pragma unroll
        for (int j = 0; j < N; ++j) v[j] += __shfl_xor(v[j], m, 64);
    }
}

// ---------- packed-key top-4 machinery ----------
// key = monotone(f32 sim) truncated to top-20 bits | (4095 - col).
__device__ __forceinline__ unsigned packKey(float v, int c) {
    unsigned u = __float_as_uint(v);
    u ^= (unsigned)((int)u >> 31) | 0x80000000u;   // monotone total order
    return (u & 0xFFFFF000u) | (unsigned)(4095 - c);
}

__device__ __forceinline__ void ceDesc(unsigned &a, unsigned &b) {
    unsigned mn = a > b ? b : a;
    a = a > b ? a : b;
    b = mn;
}

__device__ __forceinline__ void sort4(unsigned k[4]) {
    ceDesc(k[0], k[1]); ceDesc(k[2], k[3]);
    ceDesc(k[0], k[2]); ceDesc(k[1], k[3]);
    ceDesc(k[1], k[2]);
}

__device__ __forceinline__ void merge4(unsigned k[4],
                                       unsigned b0, unsigned b1,
                                       unsigned b2, unsigned b3) {
    k[0] = k[0] > b3 ? k[0] : b3;
    k[1] = k[1] > b2 ? k[1] : b2;
    k[2] = k[2] > b1 ? k[2] : b1;
    k[3] = k[3] > b0 ? k[3] : b0;
    ceDesc(k[0], k[2]); ceDesc(k[1], k[3]);
    ceDesc(k[0], k[1]); ceDesc(k[2], k[3]);
}

__device__ __forceinline__ void merge4Shfl(unsigned k[4], int m) {
    unsigned b0 = __shfl_xor(k[0], m, 64);
    unsigned b1 = __shfl_xor(k[1], m, 64);
    unsigned b2 = __shfl_xor(k[2], m, 64);
    unsigned b3 = __shfl_xor(k[3], m, 64);
    merge4(k, b0, b1, b2, b3);
}

// ---------------- init: resid = x, qout = 0 ----------------
__global__ void initK(const float* __restrict__ x, float* __restrict__ resid,
                      float* __restrict__ dout) {
    int i = blockIdx.x * blockDim.x + threadIdx.x;
    int stride = gridDim.x * blockDim.x;
    for (; i < QOUT_SZ; i += stride) { resid[i] = x[i]; dout[i] = 0.0f; }
}

// ---------------- implicit_cb = codebooks[q] @ weights[q]^T ----------------
__global__ __launch_bounds__(256) void gemmCbK(const float* __restrict__ A,
                                               const float* __restrict__ W,
                                               float* __restrict__ out) {
    __shared__ float As[32][64];
    __shared__ float Bs[32][64];
    int t = threadIdx.x;
    int tx = t & 15, ty = t >> 4;
    int cBase = blockIdx.x * 64;
    int dBase = blockIdx.y * 64;
    int f = t & 7;
    int mq = t >> 3;
    float acc[4][4] = {};
    for (int k0 = 0; k0 < DD; k0 += 32) {
        __syncthreads();
#pragma unroll
        for (int p = 0; p < 2; ++p) {
            int m = mq + p * 32;
            float4 av = *(const float4*)&A[(size_t)(cBase + m) * DD + k0 + f * 4];
            As[f*4+0][m] = av.x; As[f*4+1][m] = av.y; As[f*4+2][m] = av.z; As[f*4+3][m] = av.w;
            float4 wv = *(const float4*)&W[(size_t)(dBase + m) * DD + k0 + f * 4];
            Bs[f*4+0][m] = wv.x; Bs[f*4+1][m] = wv.y; Bs[f*4+2][m] = wv.z; Bs[f*4+3][m] = wv.w;
        }
        __syncthreads();
#pragma unroll
        for (int kk = 0; kk < 32; ++kk) {
            float4 a4 = *(const float4*)&As[kk][ty * 4];
            float4 b4 = *(const float4*)&Bs[kk][tx * 4];
            float a[4] = {a4.x, a4.y, a4.z, a4.w};
            float b[4] = {b4.x, b4.y, b4.z, b4.w};
#pragma unroll
            for (int i = 0; i < 4; ++i)
#pragma unroll
                for (int j = 0; j < 4; ++j) acc[i][j] += a[i] * b[j];
        }
    }
#pragma unroll
    for (int i = 0; i < 4; ++i) {
        float4 v = make_float4(acc[i][0], acc[i][1], acc[i][2], acc[i][3]);
        *(float4*)&out[(size_t)(cBase + ty * 4 + i) * DD + dBase + tx * 4] = v;
    }
}

// ------- normalize cbn rows in place + emit f16 copy (one wave/row) ----------
__global__ void rowNormCvtK(float* __restrict__ buf, _Float16* __restrict__ bf16) {
    int wave = threadIdx.x >> 6, lane = threadIdx.x & 63;
    int row = blockIdx.x * 4 + wave;
    float* p = buf + (size_t)row * DD;
    float4 v0 = *(float4*)&p[lane * 8];
    float4 v1 = *(float4*)&p[lane * 8 + 4];
    float ss = v0.x*v0.x + v0.y*v0.y + v0.z*v0.z + v0.w*v0.w
             + v1.x*v1.x + v1.y*v1.y + v1.z*v1.z + v1.w*v1.w;
    ss = waveSum(ss);
    float nrm = fmaxf(sqrtf(ss), 1e-12f);
    float vals[8] = {v0.x/nrm, v0.y/nrm, v0.z/nrm, v0.w/nrm,
                     v1.x/nrm, v1.y/nrm, v1.z/nrm, v1.w/nrm};
    *(float4*)&p[lane * 8]     = make_float4(vals[0], vals[1], vals[2], vals[3]);
    *(float4*)&p[lane * 8 + 4] = make_float4(vals[4], vals[5], vals[6], vals[7]);
    f16x8 hv;
#pragma unroll
    for (int j = 0; j < 8; ++j) hv[j] = (_Float16)vals[j];
    *(f16x8*)&bf16[(size_t)row * DD + lane * 8] = hv;
}

// ------- resid row norms + f16 copy of RAW resid (q=0 only) ------------------
__global__ void residCvtK(const float* __restrict__ resid,
                          float* __restrict__ rnrm, _Float16* __restrict__ af16) {
    int wave = threadIdx.x >> 6, lane = threadIdx.x & 63;
    int row = blockIdx.x * 4 + wave;
    const float* p = resid + (size_t)row * DD;
    float4 v0 = *(const float4*)&p[lane * 8];
    float4 v1 = *(const float4*)&p[lane * 8 + 4];
    float vals[8] = {v0.x, v0.y, v0.z, v0.w, v1.x, v1.y, v1.z, v1.w};
    float ss = 0.f;
#pragma unroll
    for (int j = 0; j < 8; ++j) ss += vals[j] * vals[j];
    ss = waveSum(ss);
    if (lane == 0) rnrm[row] = fmaxf(sqrtf(ss), 1e-12f);
    f16x8 hv;
#pragma unroll
    for (int j = 0; j < 8; ++j) hv[j] = (_Float16)vals[j];
    *(f16x8*)&af16[(size_t)row * DD + lane * 8] = hv;
}

// ---------------- single-pass f16 MFMA sim GEMM + fused top-4 ----------------
// R3: m97 geometry (learn_hip-verified 912 TF / 37% MfmaUtil on gfx950):
// 256 threads / 4 waves, 128x128 block, 64x64 wave tile (acc[4][4]), BK=64,
// SINGLE-buffer LDS (32 KB -> 3+ blocks/CU), 2 barriers per K-step.
// R2 post-mortem: dbuf at 96 KB forced 1 block/CU; without cross-block
// overlap the per-K-step vmcnt(0) drain was fully exposed (18.5% MfmaUtil).
// Implicit multi-block overlap beats explicit dbuf (m99/m100/m132 precedent).
// vs R1's 8-wave 32x64 tiles: LDS-read B/FLOP drops 1.5x (0.047 -> 0.031),
// 32 MFMA per barrier per wave instead of 16, 4-wave barriers instead of 8.
__global__ __launch_bounds__(256)
void simMfmaK(
    const _Float16* __restrict__ Af16, const _Float16* __restrict__ Bf16,
    unsigned* __restrict__ pk) {
    __shared__ _Float16 Alds[128 * 64];   // 16 KB
    __shared__ _Float16 Blds[128 * 64];   // 16 KB
    __shared__ unsigned sK[2][128][4];    // 4 KB
    int t = threadIdx.x, w = t >> 6, lane = t & 63;
    int rowBase = blockIdx.x * 128;
    int cBase = blockIdx.y * 128;
    int mbase = (w & 1) * 64, nbase = (w >> 1) * 64;
    int l15 = lane & 15, quad = lane >> 4;

    f32x4 acc[4][4];
#pragma unroll
    for (int i = 0; i < 4; ++i)
#pragma unroll
        for (int j = 0; j < 4; ++j) acc[i][j] = (f32x4){0.f, 0.f, 0.f, 0.f};

    // staging: lane covers 16 B; 8 lanes per 128-B row; each gload_lds stages
    // 8 rows; wave w stages row-groups {8w, 8w+32, 8w+64, 8w+96}. Source chunk
    // XOR-swizzled so LDS row r holds chunk c at slot c^(r&7); dest stays
    // contiguous (wave-uniform base).
    int rsub = lane >> 3;                 // 0..7 row within an 8-row group
    int swz = (lane & 7) ^ rsub;          // source 16B-chunk index

    for (int k0 = 0; k0 < DD; k0 += 64) {
        __syncthreads();                  // all waves done reading prev tile
#pragma unroll
        for (int j = 0; j < 4; ++j) {
            int r0 = j * 32 + 8 * w;      // wave-uniform 8-row group base
            __builtin_amdgcn_global_load_lds(
                (const __attribute__((address_space(1))) void*)&Af16[(size_t)(rowBase + r0 + rsub) * DD + k0 + swz * 8],
                (__attribute__((address_space(3))) void*)&Alds[r0 * 64], 16, 0, 0);
            __builtin_amdgcn_global_load_lds(
                (const __attribute__((address_space(1))) void*)&Bf16[(size_t)(cBase + r0 + rsub) * DD + k0 + swz * 8],
                (__attribute__((address_space(3))) void*)&Blds[r0 * 64], 16, 0, 0);
        }
        __syncthreads();                  // implicit vmcnt(0): tile landed
#pragma unroll
        for (int kh = 0; kh < 2; ++kh) {
            int chunk = (kh * 4 + quad) ^ (l15 & 7);   // row&7 == l15&7 for all tiles
            f16x8 af[4], bf[4];
#pragma unroll
            for (int tm = 0; tm < 4; ++tm)
                af[tm] = *(const f16x8*)&Alds[(mbase + tm * 16 + l15) * 64 + chunk * 8];
#pragma unroll
            for (int tn = 0; tn < 4; ++tn)
                bf[tn] = *(const f16x8*)&Blds[(nbase + tn * 16 + l15) * 64 + chunk * 8];
#pragma unroll
            for (int tn = 0; tn < 4; ++tn)
#pragma unroll
                for (int tm = 0; tm < 4; ++tm)
                    acc[tm][tn] = __builtin_amdgcn_mfma_f32_16x16x32_f16(
                        af[tm], bf[tn], acc[tm][tn], 0, 0, 0);
        }
    }

    // epilogue: per wave, top-4 per row over its 64 columns, packed keys.
    // D layout: lane,reg r -> row = quad*4+r (in 16-tile), col = l15
#pragma unroll
    for (int tm = 0; tm < 4; ++tm) {
#pragma unroll
        for (int r = 0; r < 4; ++r) {
            unsigned k[4];
#pragma unroll
            for (int tn = 0; tn < 4; ++tn)
                k[tn] = packKey(acc[tm][tn][r], cBase + nbase + tn * 16 + l15);
            sort4(k);
#pragma unroll
            for (int m = 1; m < 16; m <<= 1) merge4Shfl(k, m);
            if (l15 == 0) {
                int rowl = mbase + tm * 16 + quad * 4 + r;
                int slot = w >> 1;              // which 64-col half
#pragma unroll
                for (int j = 0; j < 4; ++j) sK[slot][rowl][j] = k[j];
            }
        }
    }
    __syncthreads();
    if (t < 128) {
        unsigned k[4];
#pragma unroll
        for (int j = 0; j < 4; ++j) k[j] = sK[0][t][j];
        merge4(k, sK[1][t][0], sK[1][t][1], sK[1][t][2], sK[1][t][3]);
        size_t o = ((size_t)(rowBase + t) * NB + blockIdx.y) * 4;
#pragma unroll
        for (int j = 0; j < 4; ++j) pk[o + j] = k[j];
    }
}

// -------- finalize: merge chunk top-4s, fp32 rescore, rotation, updates,
//          and emit next-q residual f16 + rnrm (fused residCvt) --------------
__global__ void finalizeK(float* __restrict__ resid,
                          float* __restrict__ rnrm,
                          const float* __restrict__ cbn,
                          const unsigned* __restrict__ pk,
                          float* __restrict__ dout,
                          float* __restrict__ lossPart,
                          _Float16* __restrict__ af16, int q) {
    __shared__ float sL[4];
    int wave = threadIdx.x >> 6, lane = threadIdx.x & 63;
    int row = blockIdx.x * 4 + wave;
    float* xr = resid + (size_t)row * DD;
    float nrm = rnrm[row];
    float4 a0 = *(float4*)&xr[lane * 8];
    float4 a1 = *(float4*)&xr[lane * 8 + 4];
    float orig[8] = {a0.x,a0.y,a0.z,a0.w,a1.x,a1.y,a1.z,a1.w};
    float x[8];
#pragma unroll
    for (int j = 0; j < 8; ++j) x[j] = orig[j] / nrm;   // x_n per reference

    // merge 32 chunk top-4 partials (lane i < 32 loads chunk i); keys sorted desc
    unsigned k[4] = {0u, 0u, 0u, 0u};
    if (lane < NB) {
        size_t o = ((size_t)row * NB + lane) * 4;
#pragma unroll
        for (int j = 0; j < 4; ++j) k[j] = pk[o + j];
    }
#pragma unroll
    for (int m = 1; m < 32; m <<= 1) merge4Shfl(k, m);
    int cand[4];
#pragma unroll
    for (int j = 0; j < 4; ++j)
        cand[j] = 4095 - (int)(__shfl(k[j], 0, 64) & 0xFFFu);

    // exact fp32 rescore of the 4 nominated candidates on the normalized row.
    float cv[4][8];
#pragma unroll
    for (int j = 0; j < 4; ++j) {
        const float* cbj = cbn + (size_t)cand[j] * DD;
        float4 c0 = *(const float4*)&cbj[lane * 8];
        float4 c1 = *(const float4*)&cbj[lane * 8 + 4];
        cv[j][0]=c0.x; cv[j][1]=c0.y; cv[j][2]=c0.z; cv[j][3]=c0.w;
        cv[j][4]=c1.x; cv[j][5]=c1.y; cv[j][6]=c1.z; cv[j][7]=c1.w;
    }
    float s[4];
#pragma unroll
    for (int j = 0; j < 4; ++j) {
        float acc = 0.f;
#pragma unroll
        for (int e = 0; e < 8; ++e) acc += x[e] * cv[j][e];
        s[j] = acc;
    }
    waveSumN<4>(s);
    float sBest = -3e38f; int idx = 0x7fffffff, sel = 0;
#pragma unroll
    for (int j = 0; j < 4; ++j) {
        if (s[j] > sBest || (s[j] == sBest && cand[j] < idx)) {
            sBest = s[j]; idx = cand[j]; sel = j;
        }
    }

    // winning row from registers (wave-uniform sel -> cndmask tree)
    float qv[8];
#pragma unroll
    for (int e = 0; e < 8; ++e)
        qv[e] = sel == 0 ? cv[0][e] : sel == 1 ? cv[1][e]
              : sel == 2 ? cv[2][e] : cv[3][e];

    float red3[3] = {0.f, 0.f, 0.f};   // ns2, nt2, lrow
#pragma unroll
    for (int j = 0; j < 8; ++j) {
        red3[0] += x[j] * x[j];
        red3[1] += qv[j] * qv[j];
        float d = x[j] - qv[j];
        red3[2] += d * d;
    }
    waveSumN<3>(red3);
    float ns = sqrtf(red3[0]), nt = sqrtf(red3[1]), lrow = red3[2];

    float u[8], qn[8], wv[8];
    float nw2 = 0.f;
#pragma unroll
    for (int j = 0; j < 8; ++j) {
        u[j] = x[j] / ns;
        qn[j] = qv[j] / nt;
        wv[j] = u[j] + qn[j];
        nw2 += wv[j] * wv[j];
    }
    nw2 = waveSum(nw2);
    float nw = fmaxf(sqrtf(nw2), 1e-12f);
    float red2[2] = {0.f, 0.f};        // dew, deu
#pragma unroll
    for (int j = 0; j < 8; ++j) {
        wv[j] = wv[j] / nw;
        red2[0] += x[j] * wv[j];
        red2[1] += x[j] * u[j];
    }
    waveSumN<2>(red2);
    float dew = red2[0], deu = red2[1];
    float scale = nt / ns;

    float r[8], nres[8];
    float ss = 0.f;
#pragma unroll
    for (int j = 0; j < 8; ++j) {
        r[j] = (x[j] - 2.0f * dew * wv[j] + 2.0f * deu * qn[j]) * scale;
        nres[j] = orig[j] - r[j];
        ss += nres[j] * nres[j];
    }

    // residual -= r ; emit f16 residual + next rnrm (fused residCvt)
    *(float4*)&xr[lane * 8]     = make_float4(nres[0], nres[1], nres[2], nres[3]);
    *(float4*)&xr[lane * 8 + 4] = make_float4(nres[4], nres[5], nres[6], nres[7]);
    ss = waveSum(ss);
    if (lane == 0) rnrm[row] = fmaxf(sqrtf(ss), 1e-12f);
    f16x8 hv;
#pragma unroll
    for (int j = 0; j < 8; ++j) hv[j] = (_Float16)nres[j];
    *(f16x8*)&af16[(size_t)row * DD + lane * 8] = hv;

    float* op = dout + (size_t)row * DD;
    float4 o0 = *(float4*)&op[lane * 8];
    float4 o1 = *(float4*)&op[lane * 8 + 4];
    o0.x += r[0]; o0.y += r[1]; o0.z += r[2]; o0.w += r[3];
    o1.x += r[4]; o1.y += r[5]; o1.z += r[6]; o1.w += r[7];
    *(float4*)&op[lane * 8] = o0;
    *(float4*)&op[lane * 8 + 4] = o1;

    if (lane == 0) {
        dout[IDX_OFF + row * 4 + q] = (float)idx;
        sL[wave] = lrow;
    }
    __syncthreads();
    if (threadIdx.x == 0) {
        lossPart[(size_t)q * NBLK_FIN + blockIdx.x] =
            (sL[0] + sL[1] + sL[2] + sL[3]) * LOSS_COEF;
    }
}

// -------- final loss reduce: one wave per q sums its 4096 block partials -----
__global__ void lossWriteK(const float* __restrict__ lossPart,
                           float* __restrict__ dout) {
    int q = threadIdx.x >> 6, lane = threadIdx.x & 63;
    float s = 0.f;
    for (int i = lane; i < NBLK_FIN; i += 64)
        s += lossPart[(size_t)q * NBLK_FIN + i];
    s = waveSum(s);
    if (lane == 0) dout[LOSS_OFF + q] = s;
}

extern "C" void kernel_launch(void* const* d_in, const int* in_sizes, int n_in,
                              void* d_out, int out_size, void* d_ws, size_t ws_size,
                              hipStream_t stream) {
    const float* x = (const float*)d_in[0];
    const float* codebooks = (const float*)d_in[1];
    const float* weights = (const float*)d_in[2];
    float* dout = (float*)d_out;
    float* w = (float*)d_ws;

    float* resid = w + WS_RESID;
    float* cbn   = w + WS_CBN;
    float* rnrm  = w + WS_RNRM;
    unsigned* pk = (unsigned*)(w + WS_PV);
    float* lossPart = w + WS_PI;
    _Float16* f16base = (_Float16*)(w + WS_F16);
    _Float16* Af16 = f16base + F16_A;
    _Float16* Bf16 = f16base + F16_B;

    initK<<<4096, 256, 0, stream>>>(x, resid, dout);
    residCvtK<<<RR / 4, 256, 0, stream>>>(resid, rnrm, Af16);

    for (int q = 0; q < QQ; ++q) {
        gemmCbK<<<dim3(CC / 64, DD / 64), 256, 0, stream>>>(
            codebooks + (size_t)q * CC * DD, weights + (size_t)q * DD * DD, cbn);
        rowNormCvtK<<<CC / 4, 256, 0, stream>>>(cbn, Bf16);
        simMfmaK<<<dim3(RR / 128, CC / 128), 256, 0, stream>>>(Af16, Bf16, pk);
        finalizeK<<<RR / 4, 256, 0, stream>>>(resid, rnrm, cbn, pk,
                                              dout, lossPart, Af16, q);
    }
    lossWriteK<<<1, 256, 0, stream>>>(lossPart, dout);
}

// Round 5
// 872.285 us; speedup vs baseline: 1.1969x; 1.1860x over previous
//
#include <hip/hip_runtime.h>
#include <math.h>

// Problem constants
#define RR 16384        // B*N rows
#define DD 512          // feature dim
#define CC 4096         // codebook size
#define QQ 4            // num quantizers
#define NB 32           // codebook n-chunks (CC/128)
#define NG 64           // 64-col groups (CC/64) -- R4 top-2-per-group keys
#define QOUT_SZ (RR*DD)
#define IDX_OFF QOUT_SZ
#define LOSS_OFF (QOUT_SZ + RR*QQ)
#define LOSS_COEF (1.25f / 8388608.0f)
#define NBLK_FIN (RR/4)  // finalize blocks per dispatch (4096)

// Workspace layout (float offsets)
#define WS_RESID 0
#define WS_CBN   (RR*DD)                    // 8388608
#define WS_RNRM  (WS_CBN + CC*DD)           // 10485760
#define WS_PV    (WS_RNRM + RR)             // 10502144  (pk: RR*128 u32 keys)
#define WS_PI    (WS_PV + RR*32*4)          // loss partials [QQ][NBLK_FIN]
#define WS_F16   (WS_PI + RR*32*4 + 4)      // 16B aligned
// f16 region (offsets in halves from WS_F16 base)
#define F16_A 0
#define F16_B (RR*DD)

typedef _Float16 f16x8 __attribute__((ext_vector_type(8)));
typedef float f32x4 __attribute__((ext_vector_type(4)));

__device__ __forceinline__ float waveSum(float v) {
#pragma unroll
    for (int m = 1; m < 64; m <<= 1) v += __shfl_xor(v, m, 64);
    return v;
}

// interleaved N-way wave sum: N independent butterfly chains for ILP
template <int N>
__device__ __forceinline__ void waveSumN(float* v) {
#pragma unroll
    for (int m = 1; m < 64; m <<= 1) {
#pragma unroll
        for (int j = 0; j < N; ++j) v[j] += __shfl_xor(v[j], m, 64);
    }
}

// ---------- packed-key top-k machinery ----------
// key = monotone(f32 sim) truncated to top-20 bits | (4095 - col).
__device__ __forceinline__ unsigned packKey(float v, int c) {
    unsigned u = __float_as_uint(v);
    u ^= (unsigned)((int)u >> 31) | 0x80000000u;   // monotone total order
    return (u & 0xFFFFF000u) | (unsigned)(4095 - c);
}

__device__ __forceinline__ void ceDesc(unsigned &a, unsigned &b) {
    unsigned mn = a > b ? b : a;
    a = a > b ? a : b;
    b = mn;
}

// merge partner's sorted-desc 4-list into mine (bitonic top-half + sort).
__device__ __forceinline__ void merge4(unsigned k[4],
                                       unsigned b0, unsigned b1,
                                       unsigned b2, unsigned b3) {
    k[0] = k[0] > b3 ? k[0] : b3;
    k[1] = k[1] > b2 ? k[1] : b2;
    k[2] = k[2] > b1 ? k[2] : b1;
    k[3] = k[3] > b0 ? k[3] : b0;
    ceDesc(k[0], k[2]); ceDesc(k[1], k[3]);
    ceDesc(k[0], k[1]); ceDesc(k[2], k[3]);
}

__device__ __forceinline__ void merge4Shfl(unsigned k[4], int m) {
    unsigned b0 = __shfl_xor(k[0], m, 64);
    unsigned b1 = __shfl_xor(k[1], m, 64);
    unsigned b2 = __shfl_xor(k[2], m, 64);
    unsigned b3 = __shfl_xor(k[3], m, 64);
    merge4(k, b0, b1, b2, b3);
}

// ---------------- init: resid = x, qout = 0 ----------------
__global__ void initK(const float* __restrict__ x, float* __restrict__ resid,
                      float* __restrict__ dout) {
    int i = blockIdx.x * blockDim.x + threadIdx.x;
    int stride = gridDim.x * blockDim.x;
    for (; i < QOUT_SZ; i += stride) { resid[i] = x[i]; dout[i] = 0.0f; }
}

// ---------------- implicit_cb = codebooks[q] @ weights[q]^T ----------------
__global__ __launch_bounds__(256) void gemmCbK(const float* __restrict__ A,
                                               const float* __restrict__ W,
                                               float* __restrict__ out) {
    __shared__ float As[32][64];
    __shared__ float Bs[32][64];
    int t = threadIdx.x;
    int tx = t & 15, ty = t >> 4;
    int cBase = blockIdx.x * 64;
    int dBase = blockIdx.y * 64;
    int f = t & 7;
    int mq = t >> 3;
    float acc[4][4] = {};
    for (int k0 = 0; k0 < DD; k0 += 32) {
        __syncthreads();
#pragma unroll
        for (int p = 0; p < 2; ++p) {
            int m = mq + p * 32;
            float4 av = *(const float4*)&A[(size_t)(cBase + m) * DD + k0 + f * 4];
            As[f*4+0][m] = av.x; As[f*4+1][m] = av.y; As[f*4+2][m] = av.z; As[f*4+3][m] = av.w;
            float4 wv = *(const float4*)&W[(size_t)(dBase + m) * DD + k0 + f * 4];
            Bs[f*4+0][m] = wv.x; Bs[f*4+1][m] = wv.y; Bs[f*4+2][m] = wv.z; Bs[f*4+3][m] = wv.w;
        }
        __syncthreads();
#pragma unroll
        for (int kk = 0; kk < 32; ++kk) {
            float4 a4 = *(const float4*)&As[kk][ty * 4];
            float4 b4 = *(const float4*)&Bs[kk][tx * 4];
            float a[4] = {a4.x, a4.y, a4.z, a4.w};
            float b[4] = {b4.x, b4.y, b4.z, b4.w};
#pragma unroll
            for (int i = 0; i < 4; ++i)
#pragma unroll
                for (int j = 0; j < 4; ++j) acc[i][j] += a[i] * b[j];
        }
    }
#pragma unroll
    for (int i = 0; i < 4; ++i) {
        float4 v = make_float4(acc[i][0], acc[i][1], acc[i][2], acc[i][3]);
        *(float4*)&out[(size_t)(cBase + ty * 4 + i) * DD + dBase + tx * 4] = v;
    }
}

// ------- normalize cbn rows in place + emit f16 copy (one wave/row) ----------
__global__ void rowNormCvtK(float* __restrict__ buf, _Float16* __restrict__ bf16) {
    int wave = threadIdx.x >> 6, lane = threadIdx.x & 63;
    int row = blockIdx.x * 4 + wave;
    float* p = buf + (size_t)row * DD;
    float4 v0 = *(float4*)&p[lane * 8];
    float4 v1 = *(float4*)&p[lane * 8 + 4];
    float ss = v0.x*v0.x + v0.y*v0.y + v0.z*v0.z + v0.w*v0.w
             + v1.x*v1.x + v1.y*v1.y + v1.z*v1.z + v1.w*v1.w;
    ss = waveSum(ss);
    float nrm = fmaxf(sqrtf(ss), 1e-12f);
    float vals[8] = {v0.x/nrm, v0.y/nrm, v0.z/nrm, v0.w/nrm,
                     v1.x/nrm, v1.y/nrm, v1.z/nrm, v1.w/nrm};
    *(float4*)&p[lane * 8]     = make_float4(vals[0], vals[1], vals[2], vals[3]);
    *(float4*)&p[lane * 8 + 4] = make_float4(vals[4], vals[5], vals[6], vals[7]);
    f16x8 hv;
#pragma unroll
    for (int j = 0; j < 8; ++j) hv[j] = (_Float16)vals[j];
    *(f16x8*)&bf16[(size_t)row * DD + lane * 8] = hv;
}

// ------- resid row norms + f16 copy of RAW resid (q=0 only) ------------------
__global__ void residCvtK(const float* __restrict__ resid,
                          float* __restrict__ rnrm, _Float16* __restrict__ af16) {
    int wave = threadIdx.x >> 6, lane = threadIdx.x & 63;
    int row = blockIdx.x * 4 + wave;
    const float* p = resid + (size_t)row * DD;
    float4 v0 = *(const float4*)&p[lane * 8];
    float4 v1 = *(const float4*)&p[lane * 8 + 4];
    float vals[8] = {v0.x, v0.y, v0.z, v0.w, v1.x, v1.y, v1.z, v1.w};
    float ss = 0.f;
#pragma unroll
    for (int j = 0; j < 8; ++j) ss += vals[j] * vals[j];
    ss = waveSum(ss);
    if (lane == 0) rnrm[row] = fmaxf(sqrtf(ss), 1e-12f);
    f16x8 hv;
#pragma unroll
    for (int j = 0; j < 8; ++j) hv[j] = (_Float16)vals[j];
    *(f16x8*)&af16[(size_t)row * DD + lane * 8] = hv;
}

// ---------------- single-pass f16 MFMA sim GEMM + fused top-2 ----------------
// R4: main loop is R1's verified structure byte-for-byte (135.5 us, VGPR 44,
// 32 waves/CU possible): 128x128 tile, BK=64, 512 threads / 8 waves, 32x64
// wave tiles. R3 post-mortem: 64x64 tiles cost VGPR 92 -> 4 waves/SIMD cap
// (m69 halving) -> residency loss beat the LDS-traffic gain; in this short-K
// (8-step) regime wave residency dominates.
// Epilogue replaced: top-2 per 64-col group (was global top-4 per 128-chunk).
// Per row: 6-op pre-reduce + 4x merge2Shfl (2 shfl + 4 op), direct uint2
// store. No LDS merge, no extra barrier, no sK -> LDS 32 KB. Nomination
// safety: true fp32 argmax missed only if >=2 same-group cols beat it in f16
// while losing in fp32 (top-gap ~1e-2 vs key noise ~1e-4 -> ~1e-9/row).
__global__ __launch_bounds__(512)
__attribute__((amdgpu_waves_per_eu(1, 4)))
void simMfmaK(
    const _Float16* __restrict__ Af16, const _Float16* __restrict__ Bf16,
    unsigned* __restrict__ pk) {
    __shared__ _Float16 Alds[128 * 64];   // 16 KB
    __shared__ _Float16 Blds[128 * 64];   // 16 KB
    int t = threadIdx.x, w = t >> 6, lane = t & 63;
    int rowBase = blockIdx.x * 128;
    int cBase = blockIdx.y * 128;
    int mbase = (w & 3) * 32, nbase = (w >> 2) * 64;
    int l15 = lane & 15, quad = lane >> 4;

    f32x4 acc[2][4];
#pragma unroll
    for (int i = 0; i < 2; ++i)
#pragma unroll
        for (int j = 0; j < 4; ++j) acc[i][j] = (f32x4){0.f, 0.f, 0.f, 0.f};

    // staging: lane covers 16 B; 8 lanes per 128-B row; wave w stages rows
    // 8w..8w+7 (+64 on round 2). Source chunk XOR-swizzled so LDS row r holds
    // chunk c at slot c^(r&7); dest stays contiguous (wave-uniform base).
    int rsub = lane >> 3;                 // 0..7 row within the wave's 8-row group
    int swz = (lane & 7) ^ rsub;          // source 16B-chunk index

    for (int k0 = 0; k0 < DD; k0 += 64) {
        __syncthreads();
#pragma unroll
        for (int j = 0; j < 2; ++j) {
            int rA = rowBase + j * 64 + 8 * w + rsub;
            int rB = cBase + j * 64 + 8 * w + rsub;
            __builtin_amdgcn_global_load_lds(
                (const __attribute__((address_space(1))) void*)&Af16[(size_t)rA * DD + k0 + swz * 8],
                (__attribute__((address_space(3))) void*)&Alds[(j * 64 + 8 * w) * 64], 16, 0, 0);
            __builtin_amdgcn_global_load_lds(
                (const __attribute__((address_space(1))) void*)&Bf16[(size_t)rB * DD + k0 + swz * 8],
                (__attribute__((address_space(3))) void*)&Blds[(j * 64 + 8 * w) * 64], 16, 0, 0);
        }
        __syncthreads();
#pragma unroll
        for (int kh = 0; kh < 2; ++kh) {
            int chunk = (kh * 4 + quad) ^ (l15 & 7);   // row&7 == l15&7 for all tiles
            f16x8 af[2];
#pragma unroll
            for (int tm = 0; tm < 2; ++tm)
                af[tm] = *(const f16x8*)&Alds[(mbase + tm * 16 + l15) * 64 + chunk * 8];
#pragma unroll
            for (int tn = 0; tn < 4; ++tn) {
                f16x8 bf = *(const f16x8*)&Blds[(nbase + tn * 16 + l15) * 64 + chunk * 8];
#pragma unroll
                for (int tm = 0; tm < 2; ++tm)
                    acc[tm][tn] = __builtin_amdgcn_mfma_f32_16x16x32_f16(
                        af[tm], bf, acc[tm][tn], 0, 0, 0);
            }
        }
    }

    // epilogue: per wave, top-2 per row over its 64 columns, packed keys.
    // D layout: lane,reg r -> row = quad*4+r (in 16-tile), col = l15
    int gkey = (cBase >> 6) + (w >> 2);   // global 64-col group index (0..63)
#pragma unroll
    for (int tm = 0; tm < 2; ++tm) {
#pragma unroll
        for (int r = 0; r < 4; ++r) {
            unsigned t0 = packKey(acc[tm][0][r], cBase + nbase + 0 * 16 + l15);
            unsigned t1 = packKey(acc[tm][1][r], cBase + nbase + 1 * 16 + l15);
            unsigned t2 = packKey(acc[tm][2][r], cBase + nbase + 2 * 16 + l15);
            unsigned t3 = packKey(acc[tm][3][r], cBase + nbase + 3 * 16 + l15);
            // per-lane sorted top-2 of 4 keys
            ceDesc(t0, t1); ceDesc(t2, t3);
            unsigned k0 = t0 > t2 ? t0 : t2;
            unsigned mn = t0 > t2 ? t2 : t0;
            unsigned mx = t1 > t3 ? t1 : t3;
            unsigned k1 = mn > mx ? mn : mx;
            // 16-lane butterfly merge of sorted pairs
#pragma unroll
            for (int m = 1; m < 16; m <<= 1) {
                unsigned b0 = __shfl_xor(k0, m, 64);
                unsigned b1 = __shfl_xor(k1, m, 64);
                unsigned m0 = k0 > b0 ? k0 : b0;
                unsigned n0 = k0 > b0 ? b0 : k0;
                unsigned m1 = k1 > b1 ? k1 : b1;
                k0 = m0;
                k1 = n0 > m1 ? n0 : m1;
            }
            if (l15 == 0) {
                int rowg = rowBase + mbase + tm * 16 + quad * 4 + r;
                *(uint2*)&pk[(size_t)rowg * 128 + gkey * 2] = make_uint2(k0, k1);
            }
        }
    }
}

// -------- finalize: merge group top-2s, fp32 rescore, rotation, updates,
//          and emit next-q residual f16 + rnrm (fused residCvt) --------------
__global__ void finalizeK(float* __restrict__ resid,
                          float* __restrict__ rnrm,
                          const float* __restrict__ cbn,
                          const unsigned* __restrict__ pk,
                          float* __restrict__ dout,
                          float* __restrict__ lossPart,
                          _Float16* __restrict__ af16, int q) {
    __shared__ float sL[4];
    int wave = threadIdx.x >> 6, lane = threadIdx.x & 63;
    int row = blockIdx.x * 4 + wave;
    float* xr = resid + (size_t)row * DD;
    float nrm = rnrm[row];
    float4 a0 = *(float4*)&xr[lane * 8];
    float4 a1 = *(float4*)&xr[lane * 8 + 4];
    float orig[8] = {a0.x,a0.y,a0.z,a0.w,a1.x,a1.y,a1.z,a1.w};
    float x[8];
#pragma unroll
    for (int j = 0; j < 8; ++j) x[j] = orig[j] / nrm;   // x_n per reference

    // 128 keys per row (64 groups x sorted top-2); lane l holds group l's pair
    uint2 kp = *(const uint2*)&pk[(size_t)row * 128 + lane * 2];
    unsigned k[4] = {kp.x, kp.y, 0u, 0u};   // sorted desc (zeros lose to real keys)
#pragma unroll
    for (int m = 1; m < 64; m <<= 1) merge4Shfl(k, m);
    int cand[4];
#pragma unroll
    for (int j = 0; j < 4; ++j)
        cand[j] = 4095 - (int)(__shfl(k[j], 0, 64) & 0xFFFu);

    // exact fp32 rescore of the 4 nominated candidates on the normalized row.
    float cv[4][8];
#pragma unroll
    for (int j = 0; j < 4; ++j) {
        const float* cbj = cbn + (size_t)cand[j] * DD;
        float4 c0 = *(const float4*)&cbj[lane * 8];
        float4 c1 = *(const float4*)&cbj[lane * 8 + 4];
        cv[j][0]=c0.x; cv[j][1]=c0.y; cv[j][2]=c0.z; cv[j][3]=c0.w;
        cv[j][4]=c1.x; cv[j][5]=c1.y; cv[j][6]=c1.z; cv[j][7]=c1.w;
    }
    float s[4];
#pragma unroll
    for (int j = 0; j < 4; ++j) {
        float acc = 0.f;
#pragma unroll
        for (int e = 0; e < 8; ++e) acc += x[e] * cv[j][e];
        s[j] = acc;
    }
    waveSumN<4>(s);
    float sBest = -3e38f; int idx = 0x7fffffff, sel = 0;
#pragma unroll
    for (int j = 0; j < 4; ++j) {
        if (s[j] > sBest || (s[j] == sBest && cand[j] < idx)) {
            sBest = s[j]; idx = cand[j]; sel = j;
        }
    }

    // winning row from registers (wave-uniform sel -> cndmask tree)
    float qv[8];
#pragma unroll
    for (int e = 0; e < 8; ++e)
        qv[e] = sel == 0 ? cv[0][e] : sel == 1 ? cv[1][e]
              : sel == 2 ? cv[2][e] : cv[3][e];

    float red3[3] = {0.f, 0.f, 0.f};   // ns2, nt2, lrow
#pragma unroll
    for (int j = 0; j < 8; ++j) {
        red3[0] += x[j] * x[j];
        red3[1] += qv[j] * qv[j];
        float d = x[j] - qv[j];
        red3[2] += d * d;
    }
    waveSumN<3>(red3);
    float ns = sqrtf(red3[0]), nt = sqrtf(red3[1]), lrow = red3[2];

    float u[8], qn[8], wv[8];
    float nw2 = 0.f;
#pragma unroll
    for (int j = 0; j < 8; ++j) {
        u[j] = x[j] / ns;
        qn[j] = qv[j] / nt;
        wv[j] = u[j] + qn[j];
        nw2 += wv[j] * wv[j];
    }
    nw2 = waveSum(nw2);
    float nw = fmaxf(sqrtf(nw2), 1e-12f);
    float red2[2] = {0.f, 0.f};        // dew, deu
#pragma unroll
    for (int j = 0; j < 8; ++j) {
        wv[j] = wv[j] / nw;
        red2[0] += x[j] * wv[j];
        red2[1] += x[j] * u[j];
    }
    waveSumN<2>(red2);
    float dew = red2[0], deu = red2[1];
    float scale = nt / ns;

    float r[8], nres[8];
    float ss = 0.f;
#pragma unroll
    for (int j = 0; j < 8; ++j) {
        r[j] = (x[j] - 2.0f * dew * wv[j] + 2.0f * deu * qn[j]) * scale;
        nres[j] = orig[j] - r[j];
        ss += nres[j] * nres[j];
    }

    // residual -= r ; emit f16 residual + next rnrm (fused residCvt)
    *(float4*)&xr[lane * 8]     = make_float4(nres[0], nres[1], nres[2], nres[3]);
    *(float4*)&xr[lane * 8 + 4] = make_float4(nres[4], nres[5], nres[6], nres[7]);
    ss = waveSum(ss);
    if (lane == 0) rnrm[row] = fmaxf(sqrtf(ss), 1e-12f);
    f16x8 hv;
#pragma unroll
    for (int j = 0; j < 8; ++j) hv[j] = (_Float16)nres[j];
    *(f16x8*)&af16[(size_t)row * DD + lane * 8] = hv;

    float* op = dout + (size_t)row * DD;
    float4 o0 = *(float4*)&op[lane * 8];
    float4 o1 = *(float4*)&op[lane * 8 + 4];
    o0.x += r[0]; o0.y += r[1]; o0.z += r[2]; o0.w += r[3];
    o1.x += r[4]; o1.y += r[5]; o1.z += r[6]; o1.w += r[7];
    *(float4*)&op[lane * 8] = o0;
    *(float4*)&op[lane * 8 + 4] = o1;

    if (lane == 0) {
        dout[IDX_OFF + row * 4 + q] = (float)idx;
        sL[wave] = lrow;
    }
    __syncthreads();
    if (threadIdx.x == 0) {
        lossPart[(size_t)q * NBLK_FIN + blockIdx.x] =
            (sL[0] + sL[1] + sL[2] + sL[3]) * LOSS_COEF;
    }
}

// -------- final loss reduce: one wave per q sums its 4096 block partials -----
__global__ void lossWriteK(const float* __restrict__ lossPart,
                           float* __restrict__ dout) {
    int q = threadIdx.x >> 6, lane = threadIdx.x & 63;
    float s = 0.f;
    for (int i = lane; i < NBLK_FIN; i += 64)
        s += lossPart[(size_t)q * NBLK_FIN + i];
    s = waveSum(s);
    if (lane == 0) dout[LOSS_OFF + q] = s;
}

extern "C" void kernel_launch(void* const* d_in, const int* in_sizes, int n_in,
                              void* d_out, int out_size, void* d_ws, size_t ws_size,
                              hipStream_t stream) {
    const float* x = (const float*)d_in[0];
    const float* codebooks = (const float*)d_in[1];
    const float* weights = (const float*)d_in[2];
    float* dout = (float*)d_out;
    float* w = (float*)d_ws;

    float* resid = w + WS_RESID;
    float* cbn   = w + WS_CBN;
    float* rnrm  = w + WS_RNRM;
    unsigned* pk = (unsigned*)(w + WS_PV);
    float* lossPart = w + WS_PI;
    _Float16* f16base = (_Float16*)(w + WS_F16);
    _Float16* Af16 = f16base + F16_A;
    _Float16* Bf16 = f16base + F16_B;

    initK<<<4096, 256, 0, stream>>>(x, resid, dout);
    residCvtK<<<RR / 4, 256, 0, stream>>>(resid, rnrm, Af16);

    for (int q = 0; q < QQ; ++q) {
        gemmCbK<<<dim3(CC / 64, DD / 64), 256, 0, stream>>>(
            codebooks + (size_t)q * CC * DD, weights + (size_t)q * DD * DD, cbn);
        rowNormCvtK<<<CC / 4, 256, 0, stream>>>(cbn, Bf16);
        simMfmaK<<<dim3(RR / 128, CC / 128), 512, 0, stream>>>(Af16, Bf16, pk);
        finalizeK<<<RR / 4, 256, 0, stream>>>(resid, rnrm, cbn, pk,
                                              dout, lossPart, Af16, q);
    }
    lossWriteK<<<1, 256, 0, stream>>>(lossPart, dout);
}